// Round 10
// baseline (144.815 us; speedup 1.0000x reference)
//
#include <hip/hip_runtime.h>
#include <hip/hip_bf16.h>

#define NSEQ 2048
#define BATCH 4

typedef __attribute__((ext_vector_type(8))) short bf16x8;
typedef __attribute__((ext_vector_type(4))) short s16x4;
typedef __attribute__((ext_vector_type(4))) float f32x4;

static __device__ inline ushort2 pk_bf2(float a, float b) {
    __hip_bfloat162 h = __float22bfloat162_rn(make_float2(a, b));
    return *reinterpret_cast<ushort2*>(&h);
}
static __device__ inline ushort bf1(float a) { return pk_bf2(a, a).x; }

static __device__ inline ushort4 pk_bf4u(float a, float b, float c, float d) {
    ushort2 lo = pk_bf2(a, b), hi = pk_bf2(c, d);
    return make_ushort4(lo.x, lo.y, hi.x, hi.y);
}

// pack 4 fp32 -> 4 bf16 (2 VGPRs) for MFMA operand
static __device__ inline s16x4 pk_bf4(float a, float b, float c, float d) {
    __hip_bfloat162 lo = __float22bfloat162_rn(make_float2(a, b));
    __hip_bfloat162 hi = __float22bfloat162_rn(make_float2(c, d));
    uint2 u = make_uint2(*reinterpret_cast<uint*>(&lo), *reinterpret_cast<uint*>(&hi));
    return __builtin_bit_cast(s16x4, u);
}

static __device__ inline float fexp2(float x) {
#if __has_builtin(__builtin_amdgcn_exp2f)
    return __builtin_amdgcn_exp2f(x);
#else
    return __expf(x * 0.69314718056f);
#endif
}

// async 16B/lane global->LDS; lds base wave-uniform (HW writes base + lane*16)
static __device__ inline void gload_lds16(const ushort* g, ushort* l) {
    __builtin_amdgcn_global_load_lds(
        (const __attribute__((address_space(1))) unsigned int*)g,
        (__attribute__((address_space(3))) unsigned int*)l,
        16, 0, 0);
}

// ---- cvt: blocks 0..511 transpose x -> xb [b][n][256] bf16; 512..1023 convert w_qkv/w_out ----
__global__ __launch_bounds__(256)
void cvt_all(const float* __restrict__ x, const float* __restrict__ wq,
             const float* __restrict__ wo, ushort* __restrict__ xb,
             ushort* __restrict__ wqb, ushort* __restrict__ wob)
{
    const int tid = threadIdx.x;
    const int id  = blockIdx.x;
    if (id < 512) {
        const int b  = id >> 7;
        const int ct = (id & 127) >> 5;
        const int nt = id & 31;
        const int c0 = ct * 64, n0 = nt * 64;
        __shared__ __align__(16) ushort T[64][72];
        #pragma unroll
        for (int it = 0; it < 4; ++it) {
            const int c  = it * 16 + (tid >> 4);
            const int n4 = (tid & 15) * 4;
            float4 v = *(const float4*)(x + ((size_t)b * 256 + c0 + c) * NSEQ + n0 + n4);
            T[n4 + 0][c] = bf1(v.x); T[n4 + 1][c] = bf1(v.y);
            T[n4 + 2][c] = bf1(v.z); T[n4 + 3][c] = bf1(v.w);
        }
        __syncthreads();
        const int n  = tid >> 2;
        const int cg = (tid & 3) * 16;
        ushort* dst = xb + ((size_t)b * NSEQ + n0 + n) * 256 + c0 + cg;
        *(uint4*)dst       = *(const uint4*)&T[n][cg];
        *(uint4*)(dst + 8) = *(const uint4*)&T[n][cg + 8];
    } else {
        const int f = (id - 512) * 256 + tid;
        const float* s; ushort* d; int off;
        if (f < 98304) { s = wq; d = wqb; off = f; }
        else           { s = wo; d = wob; off = f - 98304; }
        float4 v = ((const float4*)s)[off];
        ((ushort4*)d)[off] = pk_bf4u(v.x, v.y, v.z, v.w);
    }
}

// ---- GEMM1 v2: qkv = w_qkv @ x. A=wqb[o][k] K=256, B=xb[b][n][k]. 128x128 tile, BK=32,
// double-buffered LDS, ONE barrier per k-iter (prefetch covered by MFMA phase).
// V-blocks (o0>=1024) use swapped MFMA operands -> C row=n, packed ushort4 stores along n.
__global__ __launch_bounds__(256)
void gemm_qkv(const ushort* __restrict__ A, const ushort* __restrict__ X,
              ushort* __restrict__ Qt, ushort* __restrict__ Kt, ushort* __restrict__ vb)
{
    const int tid  = threadIdx.x;
    const int w    = tid >> 6;
    const int lane = tid & 63;
    const int l15  = lane & 15, quad = lane >> 4;
    const int lr4  = lane >> 2, lc4 = lane & 3;     // staging: 16 rows x 4 16B-units
    const int sw2  = l15 & 3;
    const int n0 = blockIdx.x * 128, o0 = blockIdx.y * 128, b = blockIdx.z;

    __shared__ __align__(16) ushort As[2][128 * 32];   // 8 KB each
    __shared__ __align__(16) ushort Bs[2][128 * 32];

    f32x4 acc[2][8];
    const f32x4 z4 = {0.f, 0.f, 0.f, 0.f};
    #pragma unroll
    for (int mt = 0; mt < 2; ++mt)
        #pragma unroll
        for (int nt = 0; nt < 8; ++nt) acc[mt][nt] = z4;

    const ushort* Xb = X + (size_t)b * NSEQ * 256;

    // stage tile kt into buf: wave w covers rows w*32..w*32+31 (16 rows / gload)
    #define G1_STAGE(buf, kt)                                                        \
        _Pragma("unroll")                                                            \
        for (int t = 0; t < 2; ++t) {                                                \
            const int rb = w * 32 + t * 16;                                          \
            const int r  = rb + lr4;                                                 \
            const int cu = (lc4 ^ (lr4 & 3)) * 8;                                    \
            gload_lds16(A  + (size_t)(o0 + r) * 256 + (kt) * 32 + cu, &As[buf][rb * 32]); \
            gload_lds16(Xb + (size_t)(n0 + r) * 256 + (kt) * 32 + cu, &Bs[buf][rb * 32]); \
        }

    G1_STAGE(0, 0)
    __syncthreads();

    const bool isV = (o0 >= 1024);
    for (int kt = 0; kt < 8; ++kt) {
        const int p = kt & 1;
        G1_STAGE(p ^ 1, (kt + 1) & 7)
        const ushort* as = &As[p][0];
        const ushort* bs = &Bs[p][0];
        bf16x8 a0 = *(const bf16x8*)&as[(w * 32 + l15) * 32 + (quad ^ sw2) * 8];
        bf16x8 a1 = *(const bf16x8*)&as[(w * 32 + 16 + l15) * 32 + (quad ^ sw2) * 8];
        if (!isV) {
            #pragma unroll
            for (int nt = 0; nt < 8; ++nt) {
                bf16x8 bb = *(const bf16x8*)&bs[(nt * 16 + l15) * 32 + (quad ^ sw2) * 8];
                acc[0][nt] = __builtin_amdgcn_mfma_f32_16x16x32_bf16(a0, bb, acc[0][nt], 0, 0, 0);
                acc[1][nt] = __builtin_amdgcn_mfma_f32_16x16x32_bf16(a1, bb, acc[1][nt], 0, 0, 0);
            }
        } else {
            #pragma unroll
            for (int nt = 0; nt < 8; ++nt) {
                bf16x8 bb = *(const bf16x8*)&bs[(nt * 16 + l15) * 32 + (quad ^ sw2) * 8];
                acc[0][nt] = __builtin_amdgcn_mfma_f32_16x16x32_bf16(bb, a0, acc[0][nt], 0, 0, 0);
                acc[1][nt] = __builtin_amdgcn_mfma_f32_16x16x32_bf16(bb, a1, acc[1][nt], 0, 0, 0);
            }
        }
        __syncthreads();
    }

    if (!isV) {
        // Q or K: C row=o (quad*4+reg), col=n (l15). Store [bh][n][64], ushort4 along d.
        ushort* dst = (o0 < 512) ? Qt : Kt;
        const float sc = (o0 < 512) ? 0.18033688f : 1.0f;   // 0.125 * log2(e) for Q
        #pragma unroll
        for (int mt = 0; mt < 2; ++mt) {
            const int obase = (o0 & 511) + w * 32 + mt * 16;
            const int h  = obase >> 6;
            const int d0 = (obase & 63) + quad * 4;
            ushort* dh = dst + (size_t)(b * 8 + h) * NSEQ * 64;
            #pragma unroll
            for (int nt = 0; nt < 8; ++nt)
                *(ushort4*)&dh[(size_t)(n0 + nt * 16 + l15) * 64 + d0] =
                    pk_bf4u(acc[mt][nt][0] * sc, acc[mt][nt][1] * sc,
                            acc[mt][nt][2] * sc, acc[mt][nt][3] * sc);
        }
    } else {
        // V (swapped): C row=n (quad*4+reg), col=o (l15). Store vb [b][d'][n], ushort4 along n.
        #pragma unroll
        for (int mt = 0; mt < 2; ++mt) {
            const int dp = (o0 - 1024) + w * 32 + mt * 16 + l15;
            ushort* dr = vb + ((size_t)b * 512 + dp) * NSEQ;
            #pragma unroll
            for (int nt = 0; nt < 8; ++nt)
                *(ushort4*)&dr[n0 + nt * 16 + quad * 4] =
                    pk_bf4u(acc[mt][nt][0], acc[mt][nt][1],
                            acc[mt][nt][2], acc[mt][nt][3]);
        }
    }
    #undef G1_STAGE
}

// ---- flash attention v7: in-block j-split. 512 threads = 2 groups x 4 waves. (unchanged R9) ----
__global__ __launch_bounds__(512, 4)
void attn7(const ushort* __restrict__ Qt, const ushort* __restrict__ Kt,
           const ushort* __restrict__ vb, ushort* __restrict__ attnb)
{
    const int tid  = threadIdx.x;
    const int w    = tid >> 6;          // 0..7
    const int g    = w >> 2;            // j-group
    const int ww   = w & 3;             // wave within group
    const int lane = tid & 63;
    const int l15  = lane & 15;
    const int quad = lane >> 4;
    const int lr8  = lane >> 3, lc8 = lane & 7;
    const int sw   = l15 & 7;
    const int i0   = blockIdx.x * 128;
    const int h    = blockIdx.y;
    const int b    = blockIdx.z;
    const int bh   = b * 8 + h;

    __shared__ __align__(16) ushort KVs[2][2][2][64 * 64];   // [g][buf][K/V], 64 KB

    const ushort* Qrow = Qt + (size_t)bh * NSEQ * 64;
    const ushort* Krow = Kt + (size_t)bh * NSEQ * 64;
    const ushort* Vrow = vb + ((size_t)b * 512 + h * 64) * NSEQ;

    bf16x8 qf[2][2];
    #pragma unroll
    for (int mt = 0; mt < 2; ++mt)
        #pragma unroll
        for (int kk = 0; kk < 2; ++kk)
            qf[mt][kk] = *(const bf16x8*)
                &Qrow[(size_t)(i0 + ww * 32 + mt * 16 + l15) * 64 + kk * 32 + quad * 8];

    f32x4 Oacc[4][2];
    const f32x4 z4 = {0.f, 0.f, 0.f, 0.f};
    #pragma unroll
    for (int dt = 0; dt < 4; ++dt)
        #pragma unroll
        for (int mt = 0; mt < 2; ++mt) Oacc[dt][mt] = z4;
    float lacc[2] = {0.f, 0.f};

    #pragma unroll
    for (int t = 0; t < 2; ++t) {
        const int rb = ww * 16 + t * 8;
        gload_lds16(Krow + (size_t)(g * 64 + rb + lr8) * 64 + (lc8 ^ lr8) * 8,
                    &KVs[g][0][0][rb * 64]);
        gload_lds16(Vrow + (size_t)(rb + lr8) * NSEQ + g * 64 + (lc8 ^ lr8) * 8,
                    &KVs[g][0][1][rb * 64]);
    }
    __syncthreads();

    for (int it = 0; it < 16; ++it) {
        const int p  = it & 1;
        const int jn = ((2 * (it + 1) + g) & 31) * 64;
        #pragma unroll
        for (int t = 0; t < 2; ++t) {
            const int rb = ww * 16 + t * 8;
            gload_lds16(Krow + (size_t)(jn + rb + lr8) * 64 + (lc8 ^ lr8) * 8,
                        &KVs[g][p ^ 1][0][rb * 64]);
            gload_lds16(Vrow + (size_t)(rb + lr8) * NSEQ + jn + (lc8 ^ lr8) * 8,
                        &KVs[g][p ^ 1][1][rb * 64]);
        }

        const ushort* Ks = &KVs[g][p][0][0];
        const ushort* Vs = &KVs[g][p][1][0];

        f32x4 ST[2][4];
        #pragma unroll
        for (int jt = 0; jt < 4; ++jt) {
            bf16x8 kf0 = *(const bf16x8*)&Ks[(jt * 16 + l15) * 64 + ((0 + quad) ^ sw) * 8];
            bf16x8 kf1 = *(const bf16x8*)&Ks[(jt * 16 + l15) * 64 + ((4 + quad) ^ sw) * 8];
            #pragma unroll
            for (int mt = 0; mt < 2; ++mt) {
                ST[mt][jt] = __builtin_amdgcn_mfma_f32_16x16x32_bf16(kf0, qf[mt][0], z4, 0, 0, 0);
                ST[mt][jt] = __builtin_amdgcn_mfma_f32_16x16x32_bf16(kf1, qf[mt][1], ST[mt][jt], 0, 0, 0);
            }
        }

        s16x4 pb[2][4];
        #pragma unroll
        for (int mt = 0; mt < 2; ++mt) {
            #pragma unroll
            for (int jt = 0; jt < 4; ++jt) {
                float p0 = fexp2(ST[mt][jt][0]);
                float p1 = fexp2(ST[mt][jt][1]);
                float p2 = fexp2(ST[mt][jt][2]);
                float p3 = fexp2(ST[mt][jt][3]);
                lacc[mt] += (p0 + p1) + (p2 + p3);
                pb[mt][jt] = pk_bf4(p0, p1, p2, p3);
            }
        }

        #pragma unroll
        for (int jt = 0; jt < 4; ++jt) {
            #pragma unroll
            for (int dt = 0; dt < 4; ++dt) {
                s16x4 vf = *(const s16x4*)
                    &Vs[(dt * 16 + l15) * 64 + ((2 * jt + (quad >> 1)) ^ sw) * 8 + (quad & 1) * 4];
                Oacc[dt][0] = __builtin_amdgcn_mfma_f32_16x16x16bf16_1k(vf, pb[0][jt], Oacc[dt][0], 0, 0, 0);
                Oacc[dt][1] = __builtin_amdgcn_mfma_f32_16x16x16bf16_1k(vf, pb[1][jt], Oacc[dt][1], 0, 0, 0);
            }
        }

        __syncthreads();
    }

    #pragma unroll
    for (int mt = 0; mt < 2; ++mt) {
        lacc[mt] += __shfl_xor(lacc[mt], 16, 64);
        lacc[mt] += __shfl_xor(lacc[mt], 32, 64);
    }

    float* M  = (float*)KVs;
    float* Lm = M + 4 * 64 * 36;
    const int slot = (ww * 64 + lane) * 36;
    if (g == 1) {
        #pragma unroll
        for (int dt = 0; dt < 4; ++dt)
            #pragma unroll
            for (int mt = 0; mt < 2; ++mt)
                *(f32x4*)&M[slot + (dt * 2 + mt) * 4] = Oacc[dt][mt];
        Lm[(ww * 64 + lane) * 2 + 0] = lacc[0];
        Lm[(ww * 64 + lane) * 2 + 1] = lacc[1];
    }
    __syncthreads();
    if (g == 0) {
        float ri[2];
        #pragma unroll
        for (int mt = 0; mt < 2; ++mt)
            ri[mt] = 1.f / (lacc[mt] + Lm[(ww * 64 + lane) * 2 + mt]);
        #pragma unroll
        for (int mt = 0; mt < 2; ++mt) {
            ushort* orow = attnb + ((size_t)b * NSEQ + i0 + ww * 32 + mt * 16 + l15) * 512 + h * 64;
            #pragma unroll
            for (int dt = 0; dt < 4; ++dt) {
                f32x4 o2 = *(const f32x4*)&M[slot + (dt * 2 + mt) * 4];
                *(ushort4*)&orow[dt * 16 + quad * 4] =
                    pk_bf4u((Oacc[dt][mt][0] + o2[0]) * ri[mt],
                            (Oacc[dt][mt][1] + o2[1]) * ri[mt],
                            (Oacc[dt][mt][2] + o2[2]) * ri[mt],
                            (Oacc[dt][mt][3] + o2[3]) * ri[mt]);
            }
        }
    }
}

// ---- GEMM2 v2: out = w_out @ attn + bias. 64x64 tiles, K=512, BK=32, dbuf, 1 barrier/iter. ----
__global__ __launch_bounds__(256)
void gemm_out(const ushort* __restrict__ A, const ushort* __restrict__ X,
              const float* __restrict__ bias, float* __restrict__ Y)
{
    const int tid  = threadIdx.x;
    const int w    = tid >> 6;
    const int lane = tid & 63;
    const int l15  = lane & 15, quad = lane >> 4;
    const int lr4  = lane >> 2, lc4 = lane & 3;
    const int sw2  = l15 & 3;
    const int n0 = blockIdx.x * 64, o0 = blockIdx.y * 64, b = blockIdx.z;

    __shared__ __align__(16) ushort As[2][64 * 32];   // 4 KB each
    __shared__ __align__(16) ushort Bs[2][64 * 32];

    f32x4 acc[4];
    const f32x4 z4 = {0.f, 0.f, 0.f, 0.f};
    #pragma unroll
    for (int nt = 0; nt < 4; ++nt) acc[nt] = z4;

    const ushort* Xb = X + (size_t)b * NSEQ * 512;

    #define G2_STAGE(buf, kt)                                                         \
        {                                                                             \
            const int rb = w * 16;                                                    \
            const int r  = rb + lr4;                                                  \
            const int cu = (lc4 ^ (lr4 & 3)) * 8;                                     \
            gload_lds16(A  + (size_t)(o0 + r) * 512 + (kt) * 32 + cu, &As[buf][rb * 32]); \
            gload_lds16(Xb + (size_t)(n0 + r) * 512 + (kt) * 32 + cu, &Bs[buf][rb * 32]); \
        }

    G2_STAGE(0, 0)
    __syncthreads();

    for (int kt = 0; kt < 16; ++kt) {
        const int p = kt & 1;
        G2_STAGE(p ^ 1, (kt + 1) & 15)
        const ushort* as = &As[p][0];
        const ushort* bs = &Bs[p][0];
        bf16x8 a0 = *(const bf16x8*)&as[(w * 16 + l15) * 32 + (quad ^ sw2) * 8];
        #pragma unroll
        for (int nt = 0; nt < 4; ++nt) {
            bf16x8 bb = *(const bf16x8*)&bs[(nt * 16 + l15) * 32 + (quad ^ sw2) * 8];
            acc[nt] = __builtin_amdgcn_mfma_f32_16x16x32_bf16(a0, bb, acc[nt], 0, 0, 0);
        }
        __syncthreads();
    }

    float* Yb = Y + (size_t)b * 256 * NSEQ;
    #pragma unroll
    for (int reg = 0; reg < 4; ++reg) {
        const int o = o0 + w * 16 + quad * 4 + reg;
        const float bi = bias[o];
        #pragma unroll
        for (int nt = 0; nt < 4; ++nt)
            Yb[(size_t)o * NSEQ + n0 + nt * 16 + l15] = acc[nt][reg] + bi;
    }
    #undef G2_STAGE
}

extern "C" void kernel_launch(void* const* d_in, const int* in_sizes, int n_in,
                              void* d_out, int out_size, void* d_ws, size_t ws_size,
                              hipStream_t stream)
{
    const float* x     = (const float*)d_in[0];
    const float* w_qkv = (const float*)d_in[1];
    const float* w_out = (const float*)d_in[2];
    const float* b_out = (const float*)d_in[3];
    float* out = (float*)d_out;

    ushort* xb    = (ushort*)d_ws;                 // 2,097,152  [b][n][256]
    ushort* wqb   = xb    + 2097152;               //   393,216
    ushort* wob   = wqb   + 393216;                //   131,072
    ushort* Qt    = wob   + 131072;                // 4,194,304  [bh][n][64]
    ushort* Kt    = Qt    + 4194304;               // 4,194,304  [bh][n][64]
    ushort* vb    = Kt    + 4194304;               // 4,194,304  [b][512][n]
    ushort* attnb = vb    + 4194304;               // 4,194,304  [b][n][512]

    cvt_all<<<1024, 256, 0, stream>>>(x, w_qkv, w_out, xb, wqb, wob);

    gemm_qkv<<<dim3(16, 12, BATCH), 256, 0, stream>>>(wqb, xb, Qt, Kt, vb);

    attn7<<<dim3(16, 8, BATCH), 512, 0, stream>>>(Qt, Kt, vb, attnb);

    gemm_out<<<dim3(32, 4, BATCH), 256, 0, stream>>>(wob, attnb, b_out, out);
}

// Round 11
// 144.414 us; speedup vs baseline: 1.0028x; 1.0028x over previous
//
#include <hip/hip_runtime.h>
#include <hip/hip_bf16.h>

#define NSEQ 2048
#define BATCH 4

typedef __attribute__((ext_vector_type(8))) short bf16x8;
typedef __attribute__((ext_vector_type(4))) short s16x4;
typedef __attribute__((ext_vector_type(4))) float f32x4;

static __device__ inline ushort2 pk_bf2(float a, float b) {
    __hip_bfloat162 h = __float22bfloat162_rn(make_float2(a, b));
    return *reinterpret_cast<ushort2*>(&h);
}
static __device__ inline uint pk2u(float a, float b) {
    __hip_bfloat162 h = __float22bfloat162_rn(make_float2(a, b));
    return *reinterpret_cast<uint*>(&h);
}
static __device__ inline ushort4 pk_bf4u(float a, float b, float c, float d) {
    ushort2 lo = pk_bf2(a, b), hi = pk_bf2(c, d);
    return make_ushort4(lo.x, lo.y, hi.x, hi.y);
}
static __device__ inline s16x4 pk_bf4(float a, float b, float c, float d) {
    uint2 u = make_uint2(pk2u(a, b), pk2u(c, d));
    return __builtin_bit_cast(s16x4, u);
}
// constant-index float4 component extract (folds at compile time under unroll)
static __device__ inline float fc(float4 v, int j) {
    return j == 0 ? v.x : (j == 1 ? v.y : (j == 2 ? v.z : v.w));
}

static __device__ inline float fexp2(float x) {
#if __has_builtin(__builtin_amdgcn_exp2f)
    return __builtin_amdgcn_exp2f(x);
#else
    return __expf(x * 0.69314718056f);
#endif
}

// async 16B/lane global->LDS; lds base wave-uniform (HW writes base + lane*16)
static __device__ inline void gload_lds16(const ushort* g, ushort* l) {
    __builtin_amdgcn_global_load_lds(
        (const __attribute__((address_space(1))) unsigned int*)g,
        (__attribute__((address_space(3))) unsigned int*)l,
        16, 0, 0);
}

// ---- GEMM1 v3: qkv = w_qkv @ x, fp32 inputs, in-register bf16 cvt, dbuf LDS,
// reg-prefetch, ONE barrier per k-iter. 128x128 tile, BK=64, K=256 (4 iters).
// Q (o<512, pre-scaled) -> Qt [bh][n][64]; K -> Kt; V (swapped operands) -> vb [b][d'][n].
__global__ __launch_bounds__(256)
void gemm_qkv(const float* __restrict__ W, const float* __restrict__ x,
              ushort* __restrict__ Qt, ushort* __restrict__ Kt, ushort* __restrict__ vb)
{
    const int tid  = threadIdx.x;
    const int w    = tid >> 6;
    const int lane = tid & 63;
    const int l15  = lane & 15, quad = lane >> 4;
    const int sw   = l15 & 7;
    const int n0 = blockIdx.x * 128, o0 = blockIdx.y * 128, b = blockIdx.z;

    __shared__ __align__(16) ushort As[2][128 * 64];   // 16 KB each
    __shared__ __align__(16) ushort Bs[2][128 * 64];

    // staging maps
    const int ao = tid >> 3;           // A: row base (+s*32), 8 lanes/row
    const int ac = (tid & 7) * 8;      // A: c offset (8 floats)
    const int au = ac >> 3;            // A: 16B unit index
    const int bc = (tid >> 5) * 8;     // B: 8 c-rows base
    const int bn = (tid & 31) * 4;     // B: 4 n base
    const int bu = bc >> 3;            // B: unit index

    const float* Wb = W + (size_t)o0 * 256;
    const float* xg = x + (size_t)b * 256 * NSEQ + n0;

    float4 ar[8], br[8];

    #define G1_LOAD(kt) {                                                          \
        _Pragma("unroll")                                                          \
        for (int s = 0; s < 4; ++s) {                                              \
            const float* wp = Wb + (size_t)(s * 32 + ao) * 256 + (kt) * 64 + ac;   \
            ar[s * 2]     = *(const float4*)wp;                                    \
            ar[s * 2 + 1] = *(const float4*)(wp + 4);                              \
        }                                                                          \
        _Pragma("unroll")                                                          \
        for (int i = 0; i < 8; ++i)                                                \
            br[i] = *(const float4*)(xg + (size_t)((kt) * 64 + bc + i) * NSEQ + bn); }

    #define G1_WRITE(buf) {                                                       \
        _Pragma("unroll")                                                          \
        for (int s = 0; s < 4; ++s) {                                              \
            const int o = s * 32 + ao;                                             \
            float4 v0 = ar[s * 2], v1 = ar[s * 2 + 1];                             \
            uint4 pv = make_uint4(pk2u(v0.x, v0.y), pk2u(v0.z, v0.w),              \
                                  pk2u(v1.x, v1.y), pk2u(v1.z, v1.w));             \
            *(uint4*)&As[buf][o * 64 + (au ^ (o & 7)) * 8] = pv;                   \
        }                                                                          \
        _Pragma("unroll")                                                          \
        for (int j = 0; j < 4; ++j) {                                              \
            const int n = bn + j;                                                  \
            uint4 pv = make_uint4(pk2u(fc(br[0], j), fc(br[1], j)),                \
                                  pk2u(fc(br[2], j), fc(br[3], j)),                \
                                  pk2u(fc(br[4], j), fc(br[5], j)),                \
                                  pk2u(fc(br[6], j), fc(br[7], j)));               \
            *(uint4*)&Bs[buf][n * 64 + (bu ^ (n & 7)) * 8] = pv;                   \
        } }

    f32x4 acc[2][8];
    const f32x4 z4 = {0.f, 0.f, 0.f, 0.f};
    #pragma unroll
    for (int mt = 0; mt < 2; ++mt)
        #pragma unroll
        for (int nt = 0; nt < 8; ++nt) acc[mt][nt] = z4;

    const bool isV = (o0 >= 1024);

    // prologue: tile0 -> buf0; tile1 -> regs
    G1_LOAD(0)
    G1_WRITE(0)
    G1_LOAD(1)
    __syncthreads();

    #pragma unroll
    for (int kt = 0; kt < 4; ++kt) {
        const int p = kt & 1;
        if (kt < 3) { G1_WRITE(p ^ 1) }          // stage tile kt+1 (regs ready)
        if (kt < 2) { G1_LOAD(kt + 2) }          // prefetch tile kt+2 (covered by MFMA)
        const ushort* as = &As[p][0];
        const ushort* bs = &Bs[p][0];
        #pragma unroll
        for (int kk = 0; kk < 2; ++kk) {
            bf16x8 a0 = *(const bf16x8*)&as[(w * 32 + l15) * 64 + ((kk * 4 + quad) ^ sw) * 8];
            bf16x8 a1 = *(const bf16x8*)&as[(w * 32 + 16 + l15) * 64 + ((kk * 4 + quad) ^ sw) * 8];
            if (!isV) {
                #pragma unroll
                for (int nt = 0; nt < 8; ++nt) {
                    bf16x8 bb = *(const bf16x8*)&bs[(nt * 16 + l15) * 64 + ((kk * 4 + quad) ^ sw) * 8];
                    acc[0][nt] = __builtin_amdgcn_mfma_f32_16x16x32_bf16(a0, bb, acc[0][nt], 0, 0, 0);
                    acc[1][nt] = __builtin_amdgcn_mfma_f32_16x16x32_bf16(a1, bb, acc[1][nt], 0, 0, 0);
                }
            } else {
                #pragma unroll
                for (int nt = 0; nt < 8; ++nt) {
                    bf16x8 bb = *(const bf16x8*)&bs[(nt * 16 + l15) * 64 + ((kk * 4 + quad) ^ sw) * 8];
                    acc[0][nt] = __builtin_amdgcn_mfma_f32_16x16x32_bf16(bb, a0, acc[0][nt], 0, 0, 0);
                    acc[1][nt] = __builtin_amdgcn_mfma_f32_16x16x32_bf16(bb, a1, acc[1][nt], 0, 0, 0);
                }
            }
        }
        __syncthreads();
    }

    if (!isV) {
        // Q or K: C row=o (quad*4+reg), col=n (l15). Store [bh][n][64], ushort4 along d.
        ushort* dst = (o0 < 512) ? Qt : Kt;
        const float sc = (o0 < 512) ? 0.18033688f : 1.0f;   // 0.125 * log2(e) for Q
        #pragma unroll
        for (int mt = 0; mt < 2; ++mt) {
            const int obase = (o0 & 511) + w * 32 + mt * 16;
            const int h  = obase >> 6;
            const int d0 = (obase & 63) + quad * 4;
            ushort* dh = dst + (size_t)(b * 8 + h) * NSEQ * 64;
            #pragma unroll
            for (int nt = 0; nt < 8; ++nt)
                *(ushort4*)&dh[(size_t)(n0 + nt * 16 + l15) * 64 + d0] =
                    pk_bf4u(acc[mt][nt][0] * sc, acc[mt][nt][1] * sc,
                            acc[mt][nt][2] * sc, acc[mt][nt][3] * sc);
        }
    } else {
        // V (swapped): C row=n (quad*4+reg), col=o (l15). Store vb [b][d'][n], ushort4 along n.
        #pragma unroll
        for (int mt = 0; mt < 2; ++mt) {
            const int dp = (o0 - 1024) + w * 32 + mt * 16 + l15;
            ushort* dr = vb + ((size_t)b * 512 + dp) * NSEQ;
            #pragma unroll
            for (int nt = 0; nt < 8; ++nt)
                *(ushort4*)&dr[n0 + nt * 16 + quad * 4] =
                    pk_bf4u(acc[mt][nt][0], acc[mt][nt][1],
                            acc[mt][nt][2], acc[mt][nt][3]);
        }
    }
    #undef G1_LOAD
    #undef G1_WRITE
}

// ---- flash attention v7: in-block j-split. 512 threads = 2 groups x 4 waves. (unchanged) ----
__global__ __launch_bounds__(512, 4)
void attn7(const ushort* __restrict__ Qt, const ushort* __restrict__ Kt,
           const ushort* __restrict__ vb, ushort* __restrict__ attnb)
{
    const int tid  = threadIdx.x;
    const int w    = tid >> 6;          // 0..7
    const int g    = w >> 2;            // j-group
    const int ww   = w & 3;             // wave within group
    const int lane = tid & 63;
    const int l15  = lane & 15;
    const int quad = lane >> 4;
    const int lr8  = lane >> 3, lc8 = lane & 7;
    const int sw   = l15 & 7;
    const int i0   = blockIdx.x * 128;
    const int h    = blockIdx.y;
    const int b    = blockIdx.z;
    const int bh   = b * 8 + h;

    __shared__ __align__(16) ushort KVs[2][2][2][64 * 64];   // [g][buf][K/V], 64 KB

    const ushort* Qrow = Qt + (size_t)bh * NSEQ * 64;
    const ushort* Krow = Kt + (size_t)bh * NSEQ * 64;
    const ushort* Vrow = vb + ((size_t)b * 512 + h * 64) * NSEQ;

    bf16x8 qf[2][2];
    #pragma unroll
    for (int mt = 0; mt < 2; ++mt)
        #pragma unroll
        for (int kk = 0; kk < 2; ++kk)
            qf[mt][kk] = *(const bf16x8*)
                &Qrow[(size_t)(i0 + ww * 32 + mt * 16 + l15) * 64 + kk * 32 + quad * 8];

    f32x4 Oacc[4][2];
    const f32x4 z4 = {0.f, 0.f, 0.f, 0.f};
    #pragma unroll
    for (int dt = 0; dt < 4; ++dt)
        #pragma unroll
        for (int mt = 0; mt < 2; ++mt) Oacc[dt][mt] = z4;
    float lacc[2] = {0.f, 0.f};

    #pragma unroll
    for (int t = 0; t < 2; ++t) {
        const int rb = ww * 16 + t * 8;
        gload_lds16(Krow + (size_t)(g * 64 + rb + lr8) * 64 + (lc8 ^ lr8) * 8,
                    &KVs[g][0][0][rb * 64]);
        gload_lds16(Vrow + (size_t)(rb + lr8) * NSEQ + g * 64 + (lc8 ^ lr8) * 8,
                    &KVs[g][0][1][rb * 64]);
    }
    __syncthreads();

    for (int it = 0; it < 16; ++it) {
        const int p  = it & 1;
        const int jn = ((2 * (it + 1) + g) & 31) * 64;
        #pragma unroll
        for (int t = 0; t < 2; ++t) {
            const int rb = ww * 16 + t * 8;
            gload_lds16(Krow + (size_t)(jn + rb + lr8) * 64 + (lc8 ^ lr8) * 8,
                        &KVs[g][p ^ 1][0][rb * 64]);
            gload_lds16(Vrow + (size_t)(rb + lr8) * NSEQ + jn + (lc8 ^ lr8) * 8,
                        &KVs[g][p ^ 1][1][rb * 64]);
        }

        const ushort* Ks = &KVs[g][p][0][0];
        const ushort* Vs = &KVs[g][p][1][0];

        f32x4 ST[2][4];
        #pragma unroll
        for (int jt = 0; jt < 4; ++jt) {
            bf16x8 kf0 = *(const bf16x8*)&Ks[(jt * 16 + l15) * 64 + ((0 + quad) ^ sw) * 8];
            bf16x8 kf1 = *(const bf16x8*)&Ks[(jt * 16 + l15) * 64 + ((4 + quad) ^ sw) * 8];
            #pragma unroll
            for (int mt = 0; mt < 2; ++mt) {
                ST[mt][jt] = __builtin_amdgcn_mfma_f32_16x16x32_bf16(kf0, qf[mt][0], z4, 0, 0, 0);
                ST[mt][jt] = __builtin_amdgcn_mfma_f32_16x16x32_bf16(kf1, qf[mt][1], ST[mt][jt], 0, 0, 0);
            }
        }

        s16x4 pb[2][4];
        #pragma unroll
        for (int mt = 0; mt < 2; ++mt) {
            #pragma unroll
            for (int jt = 0; jt < 4; ++jt) {
                float p0 = fexp2(ST[mt][jt][0]);
                float p1 = fexp2(ST[mt][jt][1]);
                float p2 = fexp2(ST[mt][jt][2]);
                float p3 = fexp2(ST[mt][jt][3]);
                lacc[mt] += (p0 + p1) + (p2 + p3);
                pb[mt][jt] = pk_bf4(p0, p1, p2, p3);
            }
        }

        #pragma unroll
        for (int jt = 0; jt < 4; ++jt) {
            #pragma unroll
            for (int dt = 0; dt < 4; ++dt) {
                s16x4 vf = *(const s16x4*)
                    &Vs[(dt * 16 + l15) * 64 + ((2 * jt + (quad >> 1)) ^ sw) * 8 + (quad & 1) * 4];
                Oacc[dt][0] = __builtin_amdgcn_mfma_f32_16x16x16bf16_1k(vf, pb[0][jt], Oacc[dt][0], 0, 0, 0);
                Oacc[dt][1] = __builtin_amdgcn_mfma_f32_16x16x16bf16_1k(vf, pb[1][jt], Oacc[dt][1], 0, 0, 0);
            }
        }

        __syncthreads();
    }

    #pragma unroll
    for (int mt = 0; mt < 2; ++mt) {
        lacc[mt] += __shfl_xor(lacc[mt], 16, 64);
        lacc[mt] += __shfl_xor(lacc[mt], 32, 64);
    }

    float* M  = (float*)KVs;
    float* Lm = M + 4 * 64 * 36;
    const int slot = (ww * 64 + lane) * 36;
    if (g == 1) {
        #pragma unroll
        for (int dt = 0; dt < 4; ++dt)
            #pragma unroll
            for (int mt = 0; mt < 2; ++mt)
                *(f32x4*)&M[slot + (dt * 2 + mt) * 4] = Oacc[dt][mt];
        Lm[(ww * 64 + lane) * 2 + 0] = lacc[0];
        Lm[(ww * 64 + lane) * 2 + 1] = lacc[1];
    }
    __syncthreads();
    if (g == 0) {
        float ri[2];
        #pragma unroll
        for (int mt = 0; mt < 2; ++mt)
            ri[mt] = 1.f / (lacc[mt] + Lm[(ww * 64 + lane) * 2 + mt]);
        #pragma unroll
        for (int mt = 0; mt < 2; ++mt) {
            ushort* orow = attnb + ((size_t)b * NSEQ + i0 + ww * 32 + mt * 16 + l15) * 512 + h * 64;
            #pragma unroll
            for (int dt = 0; dt < 4; ++dt) {
                f32x4 o2 = *(const f32x4*)&M[slot + (dt * 2 + mt) * 4];
                *(ushort4*)&orow[dt * 16 + quad * 4] =
                    pk_bf4u((Oacc[dt][mt][0] + o2[0]) * ri[mt],
                            (Oacc[dt][mt][1] + o2[1]) * ri[mt],
                            (Oacc[dt][mt][2] + o2[2]) * ri[mt],
                            (Oacc[dt][mt][3] + o2[3]) * ri[mt]);
            }
        }
    }
}

// ---- GEMM2 v3: out = w_out @ attn + bias. 64x64 tile, K=512, BK=64 (8 iters),
// A (fp32 w_out) reg-prefetch + in-register cvt; B (bf16 attnb) async gload; dbuf, 1 barrier/iter.
__global__ __launch_bounds__(256)
void gemm_out(const float* __restrict__ Wo, const ushort* __restrict__ X,
              const float* __restrict__ bias, float* __restrict__ Y)
{
    const int tid  = threadIdx.x;
    const int w    = tid >> 6;
    const int lane = tid & 63;
    const int l15  = lane & 15, quad = lane >> 4;
    const int lr8  = lane >> 3, lc8 = lane & 7;
    const int sw   = l15 & 7;
    const int n0 = blockIdx.x * 64, o0 = blockIdx.y * 64, b = blockIdx.z;

    __shared__ __align__(16) ushort As[2][64 * 64];   // 8 KB each
    __shared__ __align__(16) ushort Bs[2][64 * 64];

    const int ao = tid >> 3;          // A: row base (+s*32)
    const int ac = (tid & 7) * 8;
    const int au = ac >> 3;

    const float* Wb  = Wo + (size_t)o0 * 512;
    const ushort* Xb = X + ((size_t)b * NSEQ + n0) * 512;

    float4 ar[4];

    #define G2_ALOAD(kt) {                                                        \
        _Pragma("unroll")                                                         \
        for (int s = 0; s < 2; ++s) {                                             \
            const float* wp = Wb + (size_t)(s * 32 + ao) * 512 + (kt) * 64 + ac;  \
            ar[s * 2]     = *(const float4*)wp;                                   \
            ar[s * 2 + 1] = *(const float4*)(wp + 4);                             \
        } }

    #define G2_AWRITE(buf) {                                                      \
        _Pragma("unroll")                                                         \
        for (int s = 0; s < 2; ++s) {                                             \
            const int o = s * 32 + ao;                                            \
            float4 v0 = ar[s * 2], v1 = ar[s * 2 + 1];                            \
            uint4 pv = make_uint4(pk2u(v0.x, v0.y), pk2u(v0.z, v0.w),             \
                                  pk2u(v1.x, v1.y), pk2u(v1.z, v1.w));            \
            *(uint4*)&As[buf][o * 64 + (au ^ (o & 7)) * 8] = pv;                  \
        } }

    #define G2_BGLOAD(buf, kt) {                                                  \
        _Pragma("unroll")                                                         \
        for (int t = 0; t < 2; ++t) {                                             \
            const int rb = w * 16 + t * 8;                                        \
            gload_lds16(Xb + (size_t)(rb + lr8) * 512 + (kt) * 64 + (lc8 ^ lr8) * 8, \
                        &Bs[buf][rb * 64]);                                       \
        } }

    f32x4 acc[4];
    const f32x4 z4 = {0.f, 0.f, 0.f, 0.f};
    #pragma unroll
    for (int nt = 0; nt < 4; ++nt) acc[nt] = z4;

    // prologue: tile0 -> buf0; A tile1 -> regs
    G2_ALOAD(0)
    G2_AWRITE(0)
    G2_BGLOAD(0, 0)
    G2_ALOAD(1)
    __syncthreads();

    #pragma unroll
    for (int kt = 0; kt < 8; ++kt) {
        const int p = kt & 1;
        if (kt < 7) { G2_AWRITE(p ^ 1) G2_BGLOAD(p ^ 1, kt + 1) }
        if (kt < 6) { G2_ALOAD(kt + 2) }
        const ushort* as = &As[p][0];
        const ushort* bs = &Bs[p][0];
        #pragma unroll
        for (int kk = 0; kk < 2; ++kk) {
            bf16x8 a0 = *(const bf16x8*)&as[(w * 16 + l15) * 64 + ((kk * 4 + quad) ^ sw) * 8];
            #pragma unroll
            for (int nt = 0; nt < 4; ++nt) {
                bf16x8 bb = *(const bf16x8*)&bs[(nt * 16 + l15) * 64 + ((kk * 4 + quad) ^ sw) * 8];
                acc[nt] = __builtin_amdgcn_mfma_f32_16x16x32_bf16(a0, bb, acc[nt], 0, 0, 0);
            }
        }
        __syncthreads();
    }

    float* Yb = Y + (size_t)b * 256 * NSEQ;
    #pragma unroll
    for (int reg = 0; reg < 4; ++reg) {
        const int o = o0 + w * 16 + quad * 4 + reg;
        const float bi = bias[o];
        #pragma unroll
        for (int nt = 0; nt < 4; ++nt)
            Yb[(size_t)o * NSEQ + n0 + nt * 16 + l15] = acc[nt][reg] + bi;
    }
    #undef G2_ALOAD
    #undef G2_AWRITE
    #undef G2_BGLOAD
}

extern "C" void kernel_launch(void* const* d_in, const int* in_sizes, int n_in,
                              void* d_out, int out_size, void* d_ws, size_t ws_size,
                              hipStream_t stream)
{
    const float* x     = (const float*)d_in[0];
    const float* w_qkv = (const float*)d_in[1];
    const float* w_out = (const float*)d_in[2];
    const float* b_out = (const float*)d_in[3];
    float* out = (float*)d_out;

    ushort* Qt    = (ushort*)d_ws;                 // 4,194,304  [bh][n][64]
    ushort* Kt    = Qt + 4194304;                  // 4,194,304  [bh][n][64]
    ushort* vb    = Kt + 4194304;                  // 4,194,304  [b][512][n]
    ushort* attnb = vb + 4194304;                  // 4,194,304  [b][n][512]

    gemm_qkv<<<dim3(16, 12, BATCH), 256, 0, stream>>>(w_qkv, x, Qt, Kt, vb);

    attn7<<<dim3(16, 8, BATCH), 512, 0, stream>>>(Qt, Kt, vb, attnb);

    gemm_out<<<dim3(32, 4, BATCH), 256, 0, stream>>>(w_out, attnb, b_out, out);
}